// Round 2
// baseline (709.961 us; speedup 1.0000x reference)
//
#include <hip/hip_runtime.h>
#include <hip/hip_bf16.h>

#define DEVINL __device__ __forceinline__

constexpr int Bb = 8;
constexpr int Nn = 10000;
constexpr int Ff = 256;     // F (K dim of GEMM)
constexpr int Hh = 128;     // H (N dim of GEMM)
constexpr int Ee = 320000;
constexpr int Mm = Bb * Nn; // 80000 GEMM rows

typedef __attribute__((ext_vector_type(8))) short short8;
typedef __attribute__((ext_vector_type(4))) float float4v;

DEVINL float b2f(unsigned short s) {
    unsigned int u = ((unsigned int)s) << 16;
    float f;
    __builtin_memcpy(&f, &u, 4);
    return f;
}
DEVINL unsigned short f2b(float f) {
    unsigned int u;
    __builtin_memcpy(&u, &f, 4);
    unsigned int r = (u + 0x7fffu + ((u >> 16) & 1u)) >> 16;
    return (unsigned short)r;
}

// ---------------- weight transpose+convert: w[K][H] fp32 -> wT[H][K] bf16 ----
__global__ void transpose_w_kernel(const float* __restrict__ w,
                                   unsigned short* __restrict__ wT) {
    int idx = blockIdx.x * blockDim.x + threadIdx.x;
    if (idx >= Ff * Hh) return;
    int h = idx / Ff, k = idx % Ff;
    wT[idx] = f2b(w[(size_t)k * Hh + h]);
}

// ---------------- edge histogram ----------------
__global__ void hist_kernel(const int* __restrict__ rows, int* __restrict__ counts) {
    int idx = blockIdx.x * blockDim.x + threadIdx.x;
    if (idx >= Bb * Ee) return;
    int b = idx / Ee;
    atomicAdd(&counts[b * Nn + rows[idx]], 1);
}

// ---------------- per-batch exclusive scan (1 block per batch) ----------------
__global__ __launch_bounds__(1024) void scan_kernel(const int* __restrict__ counts,
                                                    int* __restrict__ offsets,
                                                    int* __restrict__ cursor) {
    __shared__ int sm[1024];
    __shared__ int running;
    int b = blockIdx.x;
    int t = threadIdx.x;
    if (t == 0) running = 0;
    __syncthreads();
    const int* cnt = counts + b * Nn;
    int* off = offsets + b * Nn;
    int* cur = cursor + b * Nn;
    for (int base = 0; base < Nn; base += 1024) {
        int i = base + t;
        int v = (i < Nn) ? cnt[i] : 0;
        sm[t] = v;
        __syncthreads();
        for (int s = 1; s < 1024; s <<= 1) {
            int add = (t >= s) ? sm[t - s] : 0;
            __syncthreads();
            sm[t] += add;
            __syncthreads();
        }
        int excl = sm[t] - v + running;
        if (i < Nn) { off[i] = excl; cur[i] = excl; }
        __syncthreads();
        if (t == 0) running += sm[1023];
        __syncthreads();
    }
}

// ---------------- scatter edges into CSR order ----------------
__global__ void scatter_kernel(const int* __restrict__ rows, const int* __restrict__ cols,
                               const float* __restrict__ vals,
                               int* __restrict__ cursor, int* __restrict__ pcols,
                               float* __restrict__ pvals) {
    int idx = blockIdx.x * blockDim.x + threadIdx.x;
    if (idx >= Bb * Ee) return;
    int b = idx / Ee;
    int r = rows[idx];
    int pos = atomicAdd(&cursor[b * Nn + r], 1);
    size_t o = (size_t)b * Ee + pos;
    pcols[o] = cols[idx];
    pvals[o] = vals[idx];
}

// ---------------- fused dropout + GEMM (fp32 in, bf16 MFMA, bf16 xw out) -----
// xw[m][h] = sum_k (u[m][k] > 0.5 ? 2*x[m][k] : 0) * w[k][h]
// wave computes 16 rows x 128 cols; 4 waves/block -> 64 rows/block
__global__ __launch_bounds__(256) void gemm_kernel(const float* __restrict__ x,
                                                   const float* __restrict__ u,
                                                   const unsigned short* __restrict__ wT,
                                                   unsigned short* __restrict__ xw) {
    int wave = threadIdx.x >> 6;
    int lane = threadIdx.x & 63;
    int m0 = (blockIdx.x * 4 + wave) * 16;
    if (m0 >= Mm) return;
    int n = lane & 15;      // A-row / B-col within 16-tile
    int q = lane >> 4;      // quad -> k-subrange q*8..q*8+7
    int mrow = m0 + n;

    const float* xrow = x + (size_t)mrow * Ff;
    const float* urow = u + (size_t)mrow * Ff;

    float4v acc[8];
#pragma unroll
    for (int t = 0; t < 8; t++) acc[t] = {0.f, 0.f, 0.f, 0.f};

#pragma unroll
    for (int k0 = 0; k0 < Ff; k0 += 32) {
        int ka = k0 + q * 8;
        float xv[8], uv[8];
        *(float4*)&xv[0] = *(const float4*)(xrow + ka);
        *(float4*)&xv[4] = *(const float4*)(xrow + ka + 4);
        *(float4*)&uv[0] = *(const float4*)(urow + ka);
        *(float4*)&uv[4] = *(const float4*)(urow + ka + 4);
        short8 af;
#pragma unroll
        for (int j = 0; j < 8; j++) {
            float a = (uv[j] > 0.5f) ? xv[j] * 2.0f : 0.0f;
            af[j] = (short)f2b(a);
        }
#pragma unroll
        for (int t = 0; t < 8; t++) {
            const unsigned short* bp = wT + (size_t)(t * 16 + n) * Ff + ka;
            short8 bfrag = *(const short8*)bp;
            acc[t] = __builtin_amdgcn_mfma_f32_16x16x32_bf16(af, bfrag, acc[t], 0, 0, 0);
        }
    }
    // D layout: row = q*4 + r, col = t*16 + n
#pragma unroll
    for (int t = 0; t < 8; t++) {
#pragma unroll
        for (int r = 0; r < 4; r++) {
            int row = m0 + q * 4 + r;
            int col = t * 16 + n;
            xw[(size_t)row * Hh + col] = f2b(acc[t][r]);
        }
    }
}

// ---------------- SpMM: one wave per output row, fp32 out ----------------
__global__ __launch_bounds__(256) void spmm_kernel(const int* __restrict__ offsets,
                                                   const int* __restrict__ counts,
                                                   const int* __restrict__ pcols,
                                                   const float* __restrict__ pvals,
                                                   const unsigned short* __restrict__ xw,
                                                   float* __restrict__ out) {
    int wid = blockIdx.x * 4 + (threadIdx.x >> 6);
    if (wid >= Mm) return;
    int lane = threadIdx.x & 63;
    int b = wid / Nn;
    int start = offsets[wid];
    int cnt = counts[wid];
    const unsigned short* xwb = xw + (size_t)b * Nn * Hh;
    const int* pc = pcols + (size_t)b * Ee;
    const float* pv = pvals + (size_t)b * Ee;

    float a0 = 0.f, a1 = 0.f;
    for (int i = 0; i < cnt; i++) {
        int c = pc[start + i];
        float v = pv[start + i];
        unsigned int two = *(const unsigned int*)(xwb + (size_t)c * Hh + lane * 2);
        a0 += v * b2f((unsigned short)(two & 0xffffu));
        a1 += v * b2f((unsigned short)(two >> 16));
    }
    float2 res;
    res.x = a0;
    res.y = a1;
    *(float2*)(out + (size_t)wid * Hh + lane * 2) = res;
}

extern "C" void kernel_launch(void* const* d_in, const int* in_sizes, int n_in,
                              void* d_out, int out_size, void* d_ws, size_t ws_size,
                              hipStream_t stream) {
    const float* x    = (const float*)d_in[0]; // fp32 [B,N,F]
    const float* du   = (const float*)d_in[1]; // fp32 [B,N,F]
    const int*   rows = (const int*)d_in[2];   // int32 [B,E]
    const int*   cols = (const int*)d_in[3];   // int32 [B,E]
    const float* vals = (const float*)d_in[4]; // fp32 [B,E]
    const float* w    = (const float*)d_in[5]; // fp32 [F,H]
    float*       out  = (float*)d_out;         // fp32 [B,N,H]

    char* p = (char*)d_ws;
    unsigned short* xw = (unsigned short*)p; p += (size_t)Mm * Hh * 2;  // 20.48 MB
    unsigned short* wT = (unsigned short*)p; p += (size_t)Ff * Hh * 2;  // 64 KB
    int* counts  = (int*)p; p += (size_t)Bb * Nn * 4;
    int* offsets = (int*)p; p += (size_t)Bb * Nn * 4;
    int* cursor  = (int*)p; p += (size_t)Bb * Nn * 4;
    int* pcols   = (int*)p; p += (size_t)Bb * Ee * 4;                   // 10.24 MB
    float* pvals = (float*)p; p += (size_t)Bb * Ee * 4;                 // 10.24 MB

    hipMemsetAsync(counts, 0, (size_t)Bb * Nn * 4, stream);
    transpose_w_kernel<<<(Ff * Hh + 255) / 256, 256, 0, stream>>>(w, wT);
    hist_kernel<<<(Bb * Ee + 255) / 256, 256, 0, stream>>>(rows, counts);
    scan_kernel<<<Bb, 1024, 0, stream>>>(counts, offsets, cursor);
    scatter_kernel<<<(Bb * Ee + 255) / 256, 256, 0, stream>>>(rows, cols, vals, cursor,
                                                              pcols, pvals);
    gemm_kernel<<<Mm / 64, 256, 0, stream>>>(x, du, wT, xw);
    spmm_kernel<<<Mm / 4, 256, 0, stream>>>(offsets, counts, pcols, pvals, xw, out);
}

// Round 3
// 534.196 us; speedup vs baseline: 1.3290x; 1.3290x over previous
//
#include <hip/hip_runtime.h>
#include <hip/hip_bf16.h>

#define DEVINL __device__ __forceinline__

constexpr int Bb = 8;
constexpr int Nn = 10000;
constexpr int Ff = 256;     // F (K dim of GEMM)
constexpr int Hh = 128;     // H (N dim of GEMM)
constexpr int Ee = 320000;
constexpr int Mm = Bb * Nn; // 80000 GEMM rows

typedef __attribute__((ext_vector_type(8))) short short8;
typedef __attribute__((ext_vector_type(4))) float float4v;
typedef __attribute__((ext_vector_type(4))) unsigned short ushort4v;

DEVINL float b2f(unsigned short s) {
    unsigned int u = ((unsigned int)s) << 16;
    float f;
    __builtin_memcpy(&f, &u, 4);
    return f;
}
DEVINL unsigned short f2b(float f) {
    unsigned int u;
    __builtin_memcpy(&u, &f, 4);
    unsigned int r = (u + 0x7fffu + ((u >> 16) & 1u)) >> 16;
    return (unsigned short)r;
}
DEVINL float i2f(int i) {
    float f;
    __builtin_memcpy(&f, &i, 4);
    return f;
}

// ---------------- weight transpose+convert: w[K][H] fp32 -> wT[H][K] bf16 ----
__global__ void transpose_w_kernel(const float* __restrict__ w,
                                   unsigned short* __restrict__ wT) {
    int idx = blockIdx.x * blockDim.x + threadIdx.x;
    if (idx >= Ff * Hh) return;
    int h = idx / Ff, k = idx % Ff;
    wT[idx] = f2b(w[(size_t)k * Hh + h]);
}

// ---------------- edge histogram ----------------
__global__ void hist_kernel(const int* __restrict__ rows, int* __restrict__ counts) {
    int idx = blockIdx.x * blockDim.x + threadIdx.x;
    if (idx >= Bb * Ee) return;
    int b = idx / Ee;
    atomicAdd(&counts[b * Nn + rows[idx]], 1);
}

// ---------------- per-batch exclusive scan (1 block per batch) ----------------
// wave-level shfl scan + cross-wave LDS combine: 3 barriers/chunk (was 20)
__global__ __launch_bounds__(1024) void scan_kernel(const int* __restrict__ counts,
                                                    int* __restrict__ offsets,
                                                    int* __restrict__ cursor) {
    __shared__ int wsum[16];
    __shared__ int chunktot;
    __shared__ int running;
    int b = blockIdx.x;
    int t = threadIdx.x;
    int lane = t & 63, wv = t >> 6;
    if (t == 0) running = 0;
    __syncthreads();
    const int* cnt = counts + b * Nn;
    int* off = offsets + b * Nn;
    int* cur = cursor + b * Nn;
    for (int base = 0; base < Nn; base += 1024) {
        int i = base + t;
        int v = (i < Nn) ? cnt[i] : 0;
        int s = v;
#pragma unroll
        for (int d = 1; d < 64; d <<= 1) {
            int o = __shfl_up(s, d);
            if (lane >= d) s += o;
        }
        if (lane == 63) wsum[wv] = s;
        __syncthreads();
        if (wv == 0 && lane < 16) {
            int ws = wsum[lane];
            int ss = ws;
#pragma unroll
            for (int d = 1; d < 16; d <<= 1) {
                int o = __shfl_up(ss, d);
                if (lane >= d) ss += o;
            }
            if (lane == 15) chunktot = ss;
            wsum[lane] = ss - ws;   // exclusive wave prefix
        }
        __syncthreads();
        int excl = s - v + wsum[wv] + running;
        if (i < Nn) { off[i] = excl; cur[i] = excl; }
        __syncthreads();
        if (t == 0) running += chunktot;
    }
}

// ---------------- scatter edges into CSR order (col,val packed) --------------
__global__ void scatter_kernel(const int* __restrict__ rows, const int* __restrict__ cols,
                               const float* __restrict__ vals,
                               int* __restrict__ cursor, int2* __restrict__ pedge) {
    int idx = blockIdx.x * blockDim.x + threadIdx.x;
    if (idx >= Bb * Ee) return;
    int b = idx / Ee;
    int r = rows[idx];
    int pos = atomicAdd(&cursor[b * Nn + r], 1);
    int vb;
    float vf = vals[idx];
    __builtin_memcpy(&vb, &vf, 4);
    pedge[(size_t)b * Ee + pos] = make_int2(cols[idx], vb);
}

// ---------------- fused dropout + GEMM (LDS-staged bf16 MFMA) ----------------
// block: 256 threads (4 waves), 64 rows x 128 cols, K in 2 halves of 128
__global__ __launch_bounds__(256, 3) void gemm_kernel(const float* __restrict__ x,
                                                      const float* __restrict__ u,
                                                      const unsigned short* __restrict__ wT,
                                                      unsigned short* __restrict__ xw) {
    __shared__ unsigned short sA[64 * 136];   // 64 rows x (128+8) bf16
    __shared__ unsigned short sB[128 * 136];  // 128 h-rows x (128+8) bf16
    int t = threadIdx.x;
    int wave = t >> 6, lane = t & 63;
    int n = lane & 15, q = lane >> 4;
    int m0 = blockIdx.x * 64;

    float4v acc[8];
#pragma unroll
    for (int i = 0; i < 8; i++) acc[i] = {0.f, 0.f, 0.f, 0.f};

    for (int kh = 0; kh < 2; kh++) {
        // stage A: x,u fp32 coalesced -> dropout -> bf16 LDS
#pragma unroll
        for (int i = 0; i < 8; i++) {
            int idx = t + i * 256;      // 2048 float4 chunks = 64 rows x 32
            int row = idx >> 5;
            int c4 = idx & 31;
            const float* xp = x + (size_t)(m0 + row) * Ff + kh * 128 + c4 * 4;
            const float* up = u + (size_t)(m0 + row) * Ff + kh * 128 + c4 * 4;
            float4 xv = *(const float4*)xp;
            float4 uv = *(const float4*)up;
            ushort4v a;
            a.x = f2b(uv.x > 0.5f ? xv.x * 2.0f : 0.0f);
            a.y = f2b(uv.y > 0.5f ? xv.y * 2.0f : 0.0f);
            a.z = f2b(uv.z > 0.5f ? xv.z * 2.0f : 0.0f);
            a.w = f2b(uv.w > 0.5f ? xv.w * 2.0f : 0.0f);
            *(ushort4v*)(&sA[row * 136 + c4 * 4]) = a;
        }
        // stage B: wT bf16 coalesced
#pragma unroll
        for (int i = 0; i < 8; i++) {
            int idx = t + i * 256;      // 2048 ushort8 chunks = 128 rows x 16
            int h = idx >> 4;
            int kc = idx & 15;
            short8 bv = *(const short8*)(wT + (size_t)h * Ff + kh * 128 + kc * 8);
            *(short8*)(&sB[h * 136 + kc * 8]) = bv;
        }
        __syncthreads();
#pragma unroll
        for (int k0 = 0; k0 < 128; k0 += 32) {
            short8 af = *(const short8*)(&sA[(wave * 16 + n) * 136 + k0 + q * 8]);
#pragma unroll
            for (int tt = 0; tt < 8; tt++) {
                short8 bf = *(const short8*)(&sB[(tt * 16 + n) * 136 + k0 + q * 8]);
                acc[tt] = __builtin_amdgcn_mfma_f32_16x16x32_bf16(af, bf, acc[tt], 0, 0, 0);
            }
        }
        __syncthreads();
    }
    // D layout: row = q*4 + r, col = tt*16 + n
#pragma unroll
    for (int tt = 0; tt < 8; tt++) {
#pragma unroll
        for (int r = 0; r < 4; r++) {
            int row = m0 + wave * 16 + q * 4 + r;
            int col = tt * 16 + n;
            xw[(size_t)row * Hh + col] = f2b(acc[tt][r]);
        }
    }
}

// ---------------- SpMM: one wave per output row, MLP-8 gathers ---------------
__global__ __launch_bounds__(256) void spmm_kernel(const int* __restrict__ offsets,
                                                   const int* __restrict__ counts,
                                                   const int2* __restrict__ pedge,
                                                   const unsigned short* __restrict__ xw,
                                                   float* __restrict__ out) {
    int wid = blockIdx.x * 4 + (threadIdx.x >> 6);
    int lane = threadIdx.x & 63;
    int b = wid / Nn;
    int start = __builtin_amdgcn_readfirstlane(offsets[wid]);
    int cnt   = __builtin_amdgcn_readfirstlane(counts[wid]);
    const unsigned short* xwb = xw + (size_t)b * Nn * Hh;
    const int2* pe = pedge + (size_t)b * Ee + start;

    float a0[8], a1[8];
#pragma unroll
    for (int k = 0; k < 8; k++) { a0[k] = 0.f; a1[k] = 0.f; }

    for (int c0 = 0; c0 < cnt; c0 += 64) {
        int rem = cnt - c0;
        if (rem > 64) rem = 64;
        int2 e = make_int2(0, 0);          // pad: col 0, val +0.0f (no-op)
        if (lane < rem) e = pe[c0 + lane];
        int rr = (rem + 7) & ~7;
        for (int j = 0; j < rr; j += 8) {
#pragma unroll
            for (int k = 0; k < 8; k++) {
                int c  = __builtin_amdgcn_readlane(e.x, j + k);
                float v = i2f(__builtin_amdgcn_readlane(e.y, j + k));
                unsigned int two = *(const unsigned int*)(xwb + (size_t)c * Hh + lane * 2);
                a0[k] += v * b2f((unsigned short)(two & 0xffffu));
                a1[k] += v * b2f((unsigned short)(two >> 16));
            }
        }
    }
    float s0 = ((a0[0] + a0[1]) + (a0[2] + a0[3])) + ((a0[4] + a0[5]) + (a0[6] + a0[7]));
    float s1 = ((a1[0] + a1[1]) + (a1[2] + a1[3])) + ((a1[4] + a1[5]) + (a1[6] + a1[7]));
    float2 res;
    res.x = s0;
    res.y = s1;
    *(float2*)(out + (size_t)wid * Hh + lane * 2) = res;
}

extern "C" void kernel_launch(void* const* d_in, const int* in_sizes, int n_in,
                              void* d_out, int out_size, void* d_ws, size_t ws_size,
                              hipStream_t stream) {
    const float* x    = (const float*)d_in[0]; // fp32 [B,N,F]
    const float* du   = (const float*)d_in[1]; // fp32 [B,N,F]
    const int*   rows = (const int*)d_in[2];   // int32 [B,E]
    const int*   cols = (const int*)d_in[3];   // int32 [B,E]
    const float* vals = (const float*)d_in[4]; // fp32 [B,E]
    const float* w    = (const float*)d_in[5]; // fp32 [F,H]
    float*       out  = (float*)d_out;         // fp32 [B,N,H]

    char* p = (char*)d_ws;
    unsigned short* xw = (unsigned short*)p; p += (size_t)Mm * Hh * 2;  // 20.48 MB
    unsigned short* wT = (unsigned short*)p; p += (size_t)Ff * Hh * 2;  // 64 KB
    int* counts  = (int*)p; p += (size_t)Bb * Nn * 4;
    int* offsets = (int*)p; p += (size_t)Bb * Nn * 4;
    int* cursor  = (int*)p; p += (size_t)Bb * Nn * 4;
    int2* pedge  = (int2*)p; p += (size_t)Bb * Ee * 8;                  // 20.48 MB

    hipMemsetAsync(counts, 0, (size_t)Bb * Nn * 4, stream);
    transpose_w_kernel<<<(Ff * Hh + 255) / 256, 256, 0, stream>>>(w, wT);
    hist_kernel<<<(Bb * Ee + 255) / 256, 256, 0, stream>>>(rows, counts);
    scan_kernel<<<Bb, 1024, 0, stream>>>(counts, offsets, cursor);
    scatter_kernel<<<(Bb * Ee + 255) / 256, 256, 0, stream>>>(rows, cols, vals, cursor, pedge);
    gemm_kernel<<<Mm / 64, 256, 0, stream>>>(x, du, wT, xw);
    spmm_kernel<<<Mm / 4, 256, 0, stream>>>(offsets, counts, pedge, xw, out);
}